// Round 18
// baseline (1079.414 us; speedup 1.0000x reference)
//
#include <hip/hip_runtime.h>
#include <hip/hip_bf16.h>
#include <math.h>

#define CDIV(a,b) (((a)+(b)-1)/(b))

constexpr int N_   = 80000;
constexpr int NC_  = 8000;
constexpr int G_   = 16;
constexpr int C_   = 5;
constexpr int CFGF = 18;
constexpr int OPF  = 140;
constexpr int OPE  = 32;
constexpr int H_   = 32;
constexpr int NUMOPS = 120;
constexpr int CROW = C_ * CFGF;   // 90
constexpr int XROW = C_ * H_;     // 160
constexpr int NR   = N_ * C_;     // 400000
constexpr float ALPHA_ = 0.2f;
constexpr int NPG = N_ / G_;      // 5000
constexpr int EPG = NC_ / G_;     // 500

__device__ __forceinline__ float lrelu(float v) { return v >= 0.0f ? v : ALPHA_ * v; }

// nfwop[op][h] = pre_b1[h] + emb[op] @ w1[158:190]
__global__ void k_nfwop(const float* __restrict__ emb, const float* __restrict__ w1,
                        const float* __restrict__ b1, float* __restrict__ nfwop) {
    int t = blockIdx.x * blockDim.x + threadIdx.x;
    if (t >= NUMOPS * H_) return;
    int op = t >> 5, h = t & 31;
    float a = b1[h];
    for (int e = 0; e < OPE; ++e)
        a = fmaf(emb[op * OPE + e], w1[(CFGF + OPF + e) * H_ + h], a);
    nfwop[t] = a;
}

// nfw[n][:] = nfwop[op_ids[n]][:] + op_feats[n] @ w1[18:158]
__global__ void k_nfw(const float* __restrict__ opf, const int* __restrict__ op_ids,
                      const float* __restrict__ nfwop, const float* __restrict__ w1,
                      float* __restrict__ nfw) {
    int n = blockIdx.x * blockDim.x + threadIdx.x;
    if (n >= N_) return;
    float acc[H_];
    const float4* it = (const float4*)(nfwop + (size_t)op_ids[n] * H_);
    #pragma unroll
    for (int q = 0; q < 8; ++q) {
        float4 v = it[q];
        acc[4 * q + 0] = v.x; acc[4 * q + 1] = v.y; acc[4 * q + 2] = v.z; acc[4 * q + 3] = v.w;
    }
    const float4* f4 = (const float4*)(opf + (size_t)n * OPF);
    const float* wf = w1 + CFGF * H_;
    for (int kc = 0; kc < OPF / 4; ++kc) {
        float4 rv = f4[kc];
        float rs[4] = {rv.x, rv.y, rv.z, rv.w};
        #pragma unroll
        for (int j = 0; j < 4; ++j) {
            int k = kc * 4 + j;
            #pragma unroll
            for (int h = 0; h < H_; ++h) acc[h] = fmaf(rs[j], wf[k * H_ + h], acc[h]);
        }
    }
    float4* o = (float4*)(nfw + (size_t)n * H_);
    #pragma unroll
    for (int q = 0; q < 8; ++q)
        o[q] = make_float4(acc[4 * q], acc[4 * q + 1], acc[4 * q + 2], acc[4 * q + 3]);
}

// cfg[cdst[i]][j] += 100 * config_feats[i][j]
__global__ void k_cfg_scatter(const float* __restrict__ cf, const int* __restrict__ cdst,
                              float* __restrict__ cfg) {
    int t = blockIdx.x * blockDim.x + threadIdx.x;
    if (t >= NC_ * CROW) return;
    int i = t / CROW, j = t - i * CROW;
    atomicAdd(&cfg[(size_t)cdst[i] * CROW + j], 100.0f * cf[t]);
}

// degree for BOTH passes: pass0 nodes [0,N), pass1 nodes [N,2N)
__global__ void k_deg2(const int* __restrict__ s0, const int* __restrict__ d0, int E0,
                       const int* __restrict__ s1, const int* __restrict__ d1, int E1,
                       int* __restrict__ deg) {
    int e = blockIdx.x * blockDim.x + threadIdx.x;
    if (e < E0) {
        atomicAdd(&deg[s0[e]], 1);
        atomicAdd(&deg[d0[e]], 1);
    } else if (e < E0 + E1) {
        int e2 = e - E0;
        atomicAdd(&deg[N_ + s1[e2]], 1);
        atomicAdd(&deg[N_ + d1[e2]], 1);
    }
}

__global__ void k_inv2(const int* __restrict__ deg, float* __restrict__ inv) {
    int i = blockIdx.x * blockDim.x + threadIdx.x;
    if (i >= 2 * N_) return;
    inv[i] = 1.0f / sqrtf((float)(deg[i] + 1));
}

// ---- CSR build over 2N nodes ----
__global__ void k_scan1(const int* __restrict__ deg, int* __restrict__ roff, int* __restrict__ aux) {
    __shared__ int s[256];
    int t = threadIdx.x, n = blockIdx.x * 256 + t;
    int v = (n < 2 * N_) ? deg[n] : 0;
    s[t] = v; __syncthreads();
    for (int off = 1; off < 256; off <<= 1) {
        int x = (t >= off) ? s[t - off] : 0;
        __syncthreads();
        s[t] += x;
        __syncthreads();
    }
    if (n < 2 * N_) roff[n] = s[t] - v;
    if (t == 255) aux[blockIdx.x] = s[255];
}

__global__ void k_scan2(int* __restrict__ aux, int nb) {
    __shared__ int s[1024];
    int t = threadIdx.x;
    int v = (t < nb) ? aux[t] : 0;
    s[t] = v; __syncthreads();
    for (int off = 1; off < 1024; off <<= 1) {
        int x = (t >= off) ? s[t - off] : 0;
        __syncthreads();
        s[t] += x;
        __syncthreads();
    }
    if (t < nb) aux[t] = s[t] - v;
}

__global__ void k_scan3(int* __restrict__ roff, const int* __restrict__ aux,
                        int* __restrict__ cur, int total) {
    int n = blockIdx.x * blockDim.x + threadIdx.x;
    if (n < 2 * N_) {
        int r = roff[n] + aux[n >> 8];
        roff[n] = r;
        cur[n] = r;
    }
    if (n == 0) roff[2 * N_] = total;
}

__global__ void k_fill2(const int* __restrict__ s0, const int* __restrict__ d0, int E0,
                        const int* __restrict__ s1, const int* __restrict__ d1, int E1,
                        int* __restrict__ cur, int* __restrict__ col) {
    int e = blockIdx.x * blockDim.x + threadIdx.x;
    if (e < E0) {
        int s = s0[e], d = d0[e];
        col[atomicAdd(&cur[d], 1)] = s;
        col[atomicAdd(&cur[s], 1)] = d;
    } else if (e < E0 + E1) {
        int e2 = e - E0;
        int s = s1[e2], d = d1[e2];
        col[atomicAdd(&cur[N_ + d], 1)] = s;
        col[atomicAdd(&cur[N_ + s], 1)] = d;
    }
}

// colv[i] = inv of the neighbor stored at col[i] (pass-aware)
__global__ void k_colinv(const int* __restrict__ col, const float* __restrict__ inv,
                         int split, int total, float* __restrict__ colv) {
    int i = blockIdx.x * blockDim.x + threadIdx.x;
    if (i >= total) return;
    colv[i] = inv[(i >= split ? N_ : 0) + col[i]];
}

// csum[n][j2] = inv[n]*cfg[n][j2] + sum_s colv*cfg[s][j2]   (unroll-2)
__global__ void k_csum_gather(const float2* __restrict__ cfg2, const float* __restrict__ inv,
                              const int* __restrict__ roff, const int* __restrict__ col,
                              const float* __restrict__ colv, float2* __restrict__ csum2) {
    int t = blockIdx.x * blockDim.x + threadIdx.x;
    if (t >= N_ * 45) return;
    int n = t / 45, j2 = t - n * 45;
    float iv = inv[n];
    float2 a = cfg2[t];
    a.x *= iv; a.y *= iv;
    int e = roff[n], p1 = roff[n + 1];
    for (; e + 1 < p1; e += 2) {
        int s0 = col[e], s1 = col[e + 1];
        float i0 = colv[e], i1 = colv[e + 1];
        float2 v0 = cfg2[(size_t)s0 * 45 + j2];
        float2 v1 = cfg2[(size_t)s1 * 45 + j2];
        a.x = fmaf(v0.x, i0, a.x); a.y = fmaf(v0.y, i0, a.y);
        a.x = fmaf(v1.x, i1, a.x); a.y = fmaf(v1.y, i1, a.y);
    }
    if (e < p1) {
        int s0 = col[e];
        float i0 = colv[e];
        float2 v0 = cfg2[(size_t)s0 * 45 + j2];
        a.x = fmaf(v0.x, i0, a.x); a.y = fmaf(v0.y, i0, a.y);
    }
    csum2[t] = a;
}

// pre-MLP, one thread per row (row-major x)
__global__ void k_pre(const float* __restrict__ cfg, const float* __restrict__ nfw,
                      const float* __restrict__ w1, const float* __restrict__ w2,
                      const float* __restrict__ b2, float* __restrict__ x) {
    int r = blockIdx.x * blockDim.x + threadIdx.x;
    if (r >= NR) return;
    int n = r / C_;
    float h1[H_];
    const float4* nf4 = (const float4*)(nfw + (size_t)n * H_);
    #pragma unroll
    for (int q = 0; q < 8; ++q) {
        float4 v = nf4[q];
        h1[4 * q + 0] = v.x; h1[4 * q + 1] = v.y; h1[4 * q + 2] = v.z; h1[4 * q + 3] = v.w;
    }
    const float2* c2 = (const float2*)(cfg + (size_t)r * CFGF);
    for (int kc = 0; kc < CFGF / 2; ++kc) {
        float2 cv = c2[kc];
        float cs[2] = {cv.x, cv.y};
        #pragma unroll
        for (int j = 0; j < 2; ++j) {
            int k = kc * 2 + j;
            #pragma unroll
            for (int h = 0; h < H_; ++h) h1[h] = fmaf(cs[j], w1[k * H_ + h], h1[h]);
        }
    }
    #pragma unroll
    for (int h = 0; h < H_; ++h) h1[h] = lrelu(h1[h]);
    float acc[H_];
    #pragma unroll
    for (int h = 0; h < H_; ++h) acc[h] = b2[h];
    #pragma unroll
    for (int k = 0; k < H_; ++k) {
        float v = h1[k];
        #pragma unroll
        for (int h = 0; h < H_; ++h) acc[h] = fmaf(v, w2[k * H_ + h], acc[h]);
    }
    float4* o = (float4*)(x + (size_t)r * H_);
    #pragma unroll
    for (int q = 0; q < 8; ++q)
        o[q] = make_float4(lrelu(acc[4 * q]), lrelu(acc[4 * q + 1]),
                           lrelu(acc[4 * q + 2]), lrelu(acc[4 * q + 3]));
}

// FUSED gather + GC-MLP, TWO THREADS PER ROW (half-row each).
// Block 256 = 128 rows; half = tid>>7 (wave-uniform -> weights stay scalar).
// Halves exchange xs/h1 through padded LDS [128][33].
__global__ __launch_bounds__(256) void k_gcsplit(
        const float4* __restrict__ xin4, const float* __restrict__ csum,
        const float* __restrict__ inv, const int* __restrict__ roff,
        const int* __restrict__ col, const float* __restrict__ colv,
        const float* __restrict__ w1, const float* __restrict__ b1,
        const float* __restrict__ w2, const float* __restrict__ b2,
        float4* __restrict__ xout4) {
    __shared__ float sx[128][33];
    int tid = threadIdx.x;
    int half = tid >> 7, rl = tid & 127;
    int r = blockIdx.x * 128 + rl;          // NR % 128 == 0
    int n = r / C_, c = r - n * C_;
    float iv = inv[n];
    int h0 = half * 16;

    // --- csum @ w1c partial for this half's outputs (hoisted; overlaps gather) ---
    float t1[16];
    #pragma unroll
    for (int j = 0; j < 16; ++j) t1[j] = 0.0f;
    const float2* c2 = (const float2*)(csum + (size_t)r * CFGF);
    for (int kc = 0; kc < CFGF / 2; ++kc) {
        float2 cv = c2[kc];
        float cs[2] = {cv.x, cv.y};
        #pragma unroll
        for (int jj = 0; jj < 2; ++jj) {
            int k = kc * 2 + jj;
            #pragma unroll
            for (int j = 0; j < 16; ++j) t1[j] = fmaf(cs[jj], w1[k * H_ + h0 + j], t1[j]);
        }
    }

    // --- gather: this half's 16 floats (4 float4 per neighbor) ---
    float xs[16];
    const float4* sp = xin4 + (size_t)r * 8 + half * 4;
    #pragma unroll
    for (int q = 0; q < 4; ++q) {
        float4 v = sp[q];
        xs[4 * q + 0] = v.x * iv; xs[4 * q + 1] = v.y * iv;
        xs[4 * q + 2] = v.z * iv; xs[4 * q + 3] = v.w * iv;
    }
    int e = roff[n], p1 = roff[n + 1];
    for (; e + 1 < p1; e += 2) {
        int s0 = col[e], s1 = col[e + 1];
        float i0 = colv[e], i1 = colv[e + 1];
        const float4* np0 = xin4 + ((size_t)s0 * C_ + c) * 8 + half * 4;
        const float4* np1 = xin4 + ((size_t)s1 * C_ + c) * 8 + half * 4;
        #pragma unroll
        for (int q = 0; q < 4; ++q) {
            float4 v0 = np0[q];
            float4 v1 = np1[q];
            xs[4 * q + 0] = fmaf(v0.x, i0, xs[4 * q + 0]);
            xs[4 * q + 1] = fmaf(v0.y, i0, xs[4 * q + 1]);
            xs[4 * q + 2] = fmaf(v0.z, i0, xs[4 * q + 2]);
            xs[4 * q + 3] = fmaf(v0.w, i0, xs[4 * q + 3]);
            xs[4 * q + 0] = fmaf(v1.x, i1, xs[4 * q + 0]);
            xs[4 * q + 1] = fmaf(v1.y, i1, xs[4 * q + 1]);
            xs[4 * q + 2] = fmaf(v1.z, i1, xs[4 * q + 2]);
            xs[4 * q + 3] = fmaf(v1.w, i1, xs[4 * q + 3]);
        }
    }
    if (e < p1) {
        int s0 = col[e];
        float i0 = colv[e];
        const float4* np = xin4 + ((size_t)s0 * C_ + c) * 8 + half * 4;
        #pragma unroll
        for (int q = 0; q < 4; ++q) {
            float4 v = np[q];
            xs[4 * q + 0] = fmaf(v.x, i0, xs[4 * q + 0]);
            xs[4 * q + 1] = fmaf(v.y, i0, xs[4 * q + 1]);
            xs[4 * q + 2] = fmaf(v.z, i0, xs[4 * q + 2]);
            xs[4 * q + 3] = fmaf(v.w, i0, xs[4 * q + 3]);
        }
    }
    #pragma unroll
    for (int j = 0; j < 16; ++j) sx[rl][h0 + j] = xs[j];
    __syncthreads();

    // --- t1 += xs_full @ w1x (this half's 16 outputs) ---
    #pragma unroll
    for (int k = 0; k < H_; ++k) {
        float v = sx[rl][k];
        #pragma unroll
        for (int j = 0; j < 16; ++j) t1[j] = fmaf(v, w1[(CFGF + k) * H_ + h0 + j], t1[j]);
    }
    float h1[16];
    #pragma unroll
    for (int j = 0; j < 16; ++j) h1[j] = lrelu(fmaf(iv, t1[j], b1[h0 + j]));
    __syncthreads();
    #pragma unroll
    for (int j = 0; j < 16; ++j) sx[rl][h0 + j] = h1[j];
    __syncthreads();

    // --- layer 2 for this half's outputs ---
    float acc[16];
    #pragma unroll
    for (int j = 0; j < 16; ++j) acc[j] = b2[h0 + j];
    #pragma unroll
    for (int k = 0; k < H_; ++k) {
        float v = sx[rl][k];
        #pragma unroll
        for (int j = 0; j < 16; ++j) acc[j] = fmaf(v, w2[k * H_ + h0 + j], acc[j]);
    }
    float4* o = xout4 + (size_t)r * 8 + half * 4;
    #pragma unroll
    for (int q = 0; q < 4; ++q) {
        float4 v = sp[q];   // L1/L2-hot reload for residual
        v.x += lrelu(acc[4 * q + 0]); v.y += lrelu(acc[4 * q + 1]);
        v.z += lrelu(acc[4 * q + 2]); v.w += lrelu(acc[4 * q + 3]);
        o[q] = v;
    }
}

// op_sum: group via closed form n/NPG (row-major x)
__global__ void k_opsum(const float4* __restrict__ xf4, const float4* __restrict__ xb4,
                        const int* __restrict__ sel,
                        float* __restrict__ osum, float* __restrict__ cnt) {
    __shared__ float4 ls[6 * G_ * 40];
    __shared__ float lc[6 * G_];
    for (int i = threadIdx.x; i < 6 * G_ * 40; i += blockDim.x) ls[i] = make_float4(0.f, 0.f, 0.f, 0.f);
    if (threadIdx.x < 6 * G_) lc[threadIdx.x] = 0.0f;
    __syncthreads();
    int j4 = threadIdx.x % 40, i = threadIdx.x / 40;
    const int NPB = CDIV(N_, 512);
    int start = blockIdx.x * NPB;
    int end = min(start + NPB, N_);
    if (i < 6) {
        for (int n = start + i; n < end; n += 6) {
            int g = n / NPG;
            const float4* xr = sel[n] ? xb4 : xf4;
            float4 v = xr[(size_t)n * 40 + j4];
            int o = (i * G_ + g) * 40 + j4;
            float4 cacc = ls[o];
            cacc.x += v.x; cacc.y += v.y; cacc.z += v.z; cacc.w += v.w;
            ls[o] = cacc;
            if (j4 == 0) lc[i * G_ + g] += 1.0f;
        }
    }
    __syncthreads();
    for (int idx = threadIdx.x; idx < G_ * 40; idx += blockDim.x) {
        float4 s = ls[idx];
        #pragma unroll
        for (int q = 1; q < 6; ++q) {
            float4 v = ls[q * G_ * 40 + idx];
            s.x += v.x; s.y += v.y; s.z += v.z; s.w += v.w;
        }
        int g = idx / 40, j = idx - g * 40;
        float* o = osum + (size_t)g * XROW + j * 4;
        atomicAdd(o + 0, s.x); atomicAdd(o + 1, s.y);
        atomicAdd(o + 2, s.z); atomicAdd(o + 3, s.w);
    }
    if (threadIdx.x < G_) {
        float c = 0.0f;
        #pragma unroll
        for (int q = 0; q < 6; ++q) c += lc[q * G_ + threadIdx.x];
        atomicAdd(&cnt[threadIdx.x], c);
    }
}

// cfg_sum: group via closed form e/EPG
__global__ void k_cfgsum(const float4* __restrict__ xf4, const float4* __restrict__ xb4,
                         const int* __restrict__ sel, const int* __restrict__ cdst,
                         float* __restrict__ gsum) {
    __shared__ float4 ls[6 * G_ * 40];
    for (int i = threadIdx.x; i < 6 * G_ * 40; i += blockDim.x) ls[i] = make_float4(0.f, 0.f, 0.f, 0.f);
    __syncthreads();
    int j4 = threadIdx.x % 40, i = threadIdx.x / 40;
    const int EPB = CDIV(NC_, 64);
    int start = blockIdx.x * EPB;
    int end = min(start + EPB, NC_);
    if (i < 6) {
        for (int e = start + i; e < end; e += 6) {
            int g = e / EPG;
            int n = cdst[e];
            const float4* xr = sel[n] ? xb4 : xf4;
            float4 v = xr[(size_t)n * 40 + j4];
            int o = (i * G_ + g) * 40 + j4;
            float4 cacc = ls[o];
            cacc.x += v.x; cacc.y += v.y; cacc.z += v.z; cacc.w += v.w;
            ls[o] = cacc;
        }
    }
    __syncthreads();
    for (int idx = threadIdx.x; idx < G_ * 40; idx += blockDim.x) {
        float4 s = ls[idx];
        #pragma unroll
        for (int q = 1; q < 6; ++q) {
            float4 v = ls[q * G_ * 40 + idx];
            s.x += v.x; s.y += v.y; s.z += v.z; s.w += v.w;
        }
        int g = idx / 40, j = idx - g * 40;
        float* o = gsum + (size_t)g * XROW + j * 4;
        atomicAdd(o + 0, s.x); atomicAdd(o + 1, s.y);
        atomicAdd(o + 2, s.z); atomicAdd(o + 3, s.w);
    }
}

__global__ void k_final(const float* __restrict__ osum, const float* __restrict__ gsum,
                        const float* __restrict__ cnt, const float* __restrict__ pw1,
                        const float* __restrict__ pw2, float* __restrict__ out) {
    __shared__ float sw1[3 * H_ * H_];
    __shared__ float sw2[H_];
    for (int i = threadIdx.x; i < 3 * H_ * H_; i += blockDim.x) sw1[i] = pw1[i];
    if (threadIdx.x < H_) sw2[threadIdx.x] = pw2[threadIdx.x];
    __syncthreads();
    int t = threadIdx.x;
    if (t >= G_ * C_) return;
    int g = t / C_;
    const float* os = osum + (size_t)t * H_;
    const float* cs = gsum + (size_t)t * H_;
    float icnt = 1.0f / cnt[g];
    float a0[H_], a1[H_], a2[H_];
    float s1 = 0.0f, s2 = 0.0f;
    #pragma unroll
    for (int h = 0; h < H_; ++h) {
        float v1 = os[h], v2 = cs[h];
        a0[h] = v1 * icnt;
        a1[h] = v1; s1 = fmaf(v1, v1, s1);
        a2[h] = v2; s2 = fmaf(v2, v2, s2);
    }
    float r1 = 1.0f / sqrtf(fmaxf(s1, 1e-12f));
    float r2 = 1.0f / sqrtf(fmaxf(s2, 1e-12f));
    #pragma unroll
    for (int h = 0; h < H_; ++h) { a1[h] *= r1; a2[h] *= r2; }
    float o = 0.0f;
    #pragma unroll
    for (int h = 0; h < H_; ++h) {
        float a = 0.0f;
        #pragma unroll
        for (int k = 0; k < H_; ++k) a = fmaf(a0[k], sw1[k * H_ + h], a);
        #pragma unroll
        for (int k = 0; k < H_; ++k) a = fmaf(a1[k], sw1[(H_ + k) * H_ + h], a);
        #pragma unroll
        for (int k = 0; k < H_; ++k) a = fmaf(a2[k], sw1[(2 * H_ + k) * H_ + h], a);
        o = fmaf(lrelu(a), sw2[h], o);
    }
    out[t] = o;
}

extern "C" void kernel_launch(void* const* d_in, const int* in_sizes, int n_in,
                              void* d_out, int out_size, void* d_ws, size_t ws_size,
                              hipStream_t stream) {
    const float* op_feats     = (const float*)d_in[0];
    const float* config_feats = (const float*)d_in[1];
    const int*   op_ids       = (const int*)d_in[2];
    const int*   selected     = (const int*)d_in[3];
    const int*   feed_src     = (const int*)d_in[4];
    const int*   feed_dst     = (const int*)d_in[5];
    const int*   sfeed_src    = (const int*)d_in[6];
    const int*   sfeed_dst    = (const int*)d_in[7];
    const int*   config_dst   = (const int*)d_in[9];
    const int*   sconfig_dst  = (const int*)d_in[11];
    const float* emb          = (const float*)d_in[14];
    const float* pre_w1       = (const float*)d_in[15];
    const float* pre_b1       = (const float*)d_in[16];
    const float* pre_w2       = (const float*)d_in[17];
    const float* pre_b2       = (const float*)d_in[18];
    const float* gc_w1[2]     = {(const float*)d_in[19], (const float*)d_in[23]};
    const float* gc_b1[2]     = {(const float*)d_in[20], (const float*)d_in[24]};
    const float* gc_w2[2]     = {(const float*)d_in[21], (const float*)d_in[25]};
    const float* gc_b2[2]     = {(const float*)d_in[22], (const float*)d_in[26]};
    const float* post_w1      = (const float*)d_in[27];
    const float* post_w2      = (const float*)d_in[28];

    int E0 = in_sizes[4], E1 = in_sizes[6];
    int ecnt = 2 * (E0 + E1);

    char* ws = (char*)d_ws;
    size_t off = 0;
    auto alloc = [&](size_t bytes) { void* p = ws + off; off += (bytes + 255) & ~(size_t)255; return p; };
    float* nfw   = (float*)alloc((size_t)N_ * H_ * 4);
    float* nfwop = (float*)alloc((size_t)NUMOPS * H_ * 4);
    float* cfg   = (float*)alloc((size_t)N_ * CROW * 4);
    float* csum  = (float*)alloc((size_t)N_ * CROW * 4);
    float* xf    = (float*)alloc((size_t)N_ * XROW * 4);
    float* xb    = (float*)alloc((size_t)N_ * XROW * 4);
    float* xscr  = (float*)alloc((size_t)N_ * XROW * 4);
    float* invA  = (float*)alloc((size_t)2 * N_ * 4);
    int*   degA  = (int*)alloc((size_t)2 * N_ * 4);
    int*   roffA = (int*)alloc((size_t)(2 * N_ + 1) * 4);
    int*   curA  = (int*)alloc((size_t)2 * N_ * 4);
    int*   aux   = (int*)alloc((size_t)1024 * 4);
    int*   colA  = (int*)alloc((size_t)ecnt * 4);
    float* colvA = (float*)alloc((size_t)ecnt * 4);
    float* osum  = (float*)alloc((size_t)G_ * XROW * 4);
    float* gsum  = (float*)alloc((size_t)G_ * XROW * 4);
    float* cntb  = (float*)alloc((size_t)G_ * 4);

    const int NB1 = CDIV(2 * N_, 256);

    k_nfwop<<<CDIV(NUMOPS * H_, 256), 256, 0, stream>>>(emb, pre_w1, pre_b1, nfwop);
    k_nfw<<<CDIV(N_, 256), 256, 0, stream>>>(op_feats, op_ids, nfwop, pre_w1, nfw);

    // ---- shared CSR build for both passes ----
    hipMemsetAsync(degA, 0, (size_t)2 * N_ * 4, stream);
    k_deg2<<<CDIV(E0 + E1, 256), 256, 0, stream>>>(feed_src, feed_dst, E0,
                                                   sfeed_src, sfeed_dst, E1, degA);
    k_inv2<<<CDIV(2 * N_, 256), 256, 0, stream>>>(degA, invA);
    k_scan1<<<NB1, 256, 0, stream>>>(degA, roffA, aux);
    k_scan2<<<1, 1024, 0, stream>>>(aux, NB1);
    k_scan3<<<CDIV(2 * N_, 256), 256, 0, stream>>>(roffA, aux, curA, ecnt);
    k_fill2<<<CDIV(E0 + E1, 256), 256, 0, stream>>>(feed_src, feed_dst, E0,
                                                    sfeed_src, sfeed_dst, E1, curA, colA);
    k_colinv<<<CDIV(ecnt, 256), 256, 0, stream>>>(colA, invA, 2 * E0, ecnt, colvA);

    for (int p = 0; p < 2; ++p) {
        const int* cdst = p ? sconfig_dst : config_dst;
        float* x0 = p ? xb : xf;
        const float* ivp = invA + (size_t)p * N_;
        const int* roffp = roffA + (size_t)p * N_;

        hipMemsetAsync(cfg, 0, (size_t)N_ * CROW * 4, stream);
        k_cfg_scatter<<<CDIV(NC_ * CROW, 256), 256, 0, stream>>>(config_feats, cdst, cfg);
        k_csum_gather<<<CDIV(N_ * 45, 256), 256, 0, stream>>>((const float2*)cfg, ivp, roffp,
                                                              colA, colvA, (float2*)csum);
        k_pre<<<CDIV(NR, 256), 256, 0, stream>>>(cfg, nfw, pre_w1, pre_w2, pre_b2, x0);

        k_gcsplit<<<NR / 128, 256, 0, stream>>>((const float4*)x0, csum, ivp, roffp,
                                                colA, colvA, gc_w1[0], gc_b1[0],
                                                gc_w2[0], gc_b2[0], (float4*)xscr);
        k_gcsplit<<<NR / 128, 256, 0, stream>>>((const float4*)xscr, csum, ivp, roffp,
                                                colA, colvA, gc_w1[1], gc_b1[1],
                                                gc_w2[1], gc_b2[1], (float4*)x0);
    }

    hipMemsetAsync(osum, 0, (size_t)(2 * G_ * XROW + G_) * 4, stream);
    k_opsum<<<512, 256, 0, stream>>>((const float4*)xf, (const float4*)xb, selected, osum, cntb);
    k_cfgsum<<<64, 256, 0, stream>>>((const float4*)xf, (const float4*)xb, selected,
                                     config_dst, gsum);
    k_final<<<1, 128, 0, stream>>>(osum, gsum, cntb, post_w1, post_w2, (float*)d_out);
}

// Round 19
// 694.416 us; speedup vs baseline: 1.5544x; 1.5544x over previous
//
#include <hip/hip_runtime.h>
#include <hip/hip_bf16.h>
#include <math.h>

#define CDIV(a,b) (((a)+(b)-1)/(b))

constexpr int N_   = 80000;
constexpr int NC_  = 8000;
constexpr int G_   = 16;
constexpr int C_   = 5;
constexpr int CFGF = 18;
constexpr int OPF  = 140;
constexpr int OPE  = 32;
constexpr int H_   = 32;
constexpr int NUMOPS = 120;
constexpr int CROW = C_ * CFGF;   // 90
constexpr int XROW = C_ * H_;     // 160
constexpr float ALPHA_ = 0.2f;
constexpr int NPG = N_ / G_;      // 5000
constexpr int EPG = NC_ / G_;     // 500

__device__ __forceinline__ float lrelu(float v) { return v >= 0.0f ? v : ALPHA_ * v; }

// nfwop[op][h] = pre_b1[h] + emb[op] @ w1[158:190]
__global__ void k_nfwop(const float* __restrict__ emb, const float* __restrict__ w1,
                        const float* __restrict__ b1, float* __restrict__ nfwop) {
    int t = blockIdx.x * blockDim.x + threadIdx.x;
    if (t >= NUMOPS * H_) return;
    int op = t >> 5, h = t & 31;
    float a = b1[h];
    for (int e = 0; e < OPE; ++e)
        a = fmaf(emb[op * OPE + e], w1[(CFGF + OPF + e) * H_ + h], a);
    nfwop[t] = a;
}

// nfw[n][:] = nfwop[op_ids[n]][:] + op_feats[n] @ w1[18:158]
__global__ void k_nfw(const float* __restrict__ opf, const int* __restrict__ op_ids,
                      const float* __restrict__ nfwop, const float* __restrict__ w1,
                      float* __restrict__ nfw) {
    int n = blockIdx.x * blockDim.x + threadIdx.x;
    if (n >= N_) return;
    float acc[H_];
    const float4* it = (const float4*)(nfwop + (size_t)op_ids[n] * H_);
    #pragma unroll
    for (int q = 0; q < 8; ++q) {
        float4 v = it[q];
        acc[4 * q + 0] = v.x; acc[4 * q + 1] = v.y; acc[4 * q + 2] = v.z; acc[4 * q + 3] = v.w;
    }
    const float4* f4 = (const float4*)(opf + (size_t)n * OPF);
    const float* wf = w1 + CFGF * H_;
    for (int kc = 0; kc < OPF / 4; ++kc) {
        float4 rv = f4[kc];
        float rs[4] = {rv.x, rv.y, rv.z, rv.w};
        #pragma unroll
        for (int j = 0; j < 4; ++j) {
            int k = kc * 4 + j;
            #pragma unroll
            for (int h = 0; h < H_; ++h) acc[h] = fmaf(rs[j], wf[k * H_ + h], acc[h]);
        }
    }
    float4* o = (float4*)(nfw + (size_t)n * H_);
    #pragma unroll
    for (int q = 0; q < 8; ++q)
        o[q] = make_float4(acc[4 * q], acc[4 * q + 1], acc[4 * q + 2], acc[4 * q + 3]);
}

// cfg[cdst[i]][j] += 100 * config_feats[i][j]
__global__ void k_cfg_scatter(const float* __restrict__ cf, const int* __restrict__ cdst,
                              float* __restrict__ cfg) {
    int t = blockIdx.x * blockDim.x + threadIdx.x;
    if (t >= NC_ * CROW) return;
    int i = t / CROW, j = t - i * CROW;
    atomicAdd(&cfg[(size_t)cdst[i] * CROW + j], 100.0f * cf[t]);
}

// degree for BOTH passes: pass0 nodes [0,N), pass1 nodes [N,2N)
__global__ void k_deg2(const int* __restrict__ s0, const int* __restrict__ d0, int E0,
                       const int* __restrict__ s1, const int* __restrict__ d1, int E1,
                       int* __restrict__ deg) {
    int e = blockIdx.x * blockDim.x + threadIdx.x;
    if (e < E0) {
        atomicAdd(&deg[s0[e]], 1);
        atomicAdd(&deg[d0[e]], 1);
    } else if (e < E0 + E1) {
        int e2 = e - E0;
        atomicAdd(&deg[N_ + s1[e2]], 1);
        atomicAdd(&deg[N_ + d1[e2]], 1);
    }
}

__global__ void k_inv2(const int* __restrict__ deg, float* __restrict__ inv) {
    int i = blockIdx.x * blockDim.x + threadIdx.x;
    if (i >= 2 * N_) return;
    inv[i] = 1.0f / sqrtf((float)(deg[i] + 1));
}

// ---- CSR build over 2N nodes ----
__global__ void k_scan1(const int* __restrict__ deg, int* __restrict__ roff, int* __restrict__ aux) {
    __shared__ int s[256];
    int t = threadIdx.x, n = blockIdx.x * 256 + t;
    int v = (n < 2 * N_) ? deg[n] : 0;
    s[t] = v; __syncthreads();
    for (int off = 1; off < 256; off <<= 1) {
        int x = (t >= off) ? s[t - off] : 0;
        __syncthreads();
        s[t] += x;
        __syncthreads();
    }
    if (n < 2 * N_) roff[n] = s[t] - v;
    if (t == 255) aux[blockIdx.x] = s[255];
}

__global__ void k_scan2(int* __restrict__ aux, int nb) {
    __shared__ int s[1024];
    int t = threadIdx.x;
    int v = (t < nb) ? aux[t] : 0;
    s[t] = v; __syncthreads();
    for (int off = 1; off < 1024; off <<= 1) {
        int x = (t >= off) ? s[t - off] : 0;
        __syncthreads();
        s[t] += x;
        __syncthreads();
    }
    if (t < nb) aux[t] = s[t] - v;
}

__global__ void k_scan3(int* __restrict__ roff, const int* __restrict__ aux,
                        int* __restrict__ cur, int total) {
    int n = blockIdx.x * blockDim.x + threadIdx.x;
    if (n < 2 * N_) {
        int r = roff[n] + aux[n >> 8];
        roff[n] = r;
        cur[n] = r;
    }
    if (n == 0) roff[2 * N_] = total;
}

__global__ void k_fill2(const int* __restrict__ s0, const int* __restrict__ d0, int E0,
                        const int* __restrict__ s1, const int* __restrict__ d1, int E1,
                        int* __restrict__ cur, int* __restrict__ col) {
    int e = blockIdx.x * blockDim.x + threadIdx.x;
    if (e < E0) {
        int s = s0[e], d = d0[e];
        col[atomicAdd(&cur[d], 1)] = s;
        col[atomicAdd(&cur[s], 1)] = d;
    } else if (e < E0 + E1) {
        int e2 = e - E0;
        int s = s1[e2], d = d1[e2];
        col[atomicAdd(&cur[N_ + d], 1)] = s;
        col[atomicAdd(&cur[N_ + s], 1)] = d;
    }
}

// colv[i] = inv of the neighbor stored at col[i] (pass-aware). Removes one
// dependent load level from every gather loop.
__global__ void k_colinv(const int* __restrict__ col, const float* __restrict__ inv,
                         int split, int total, float* __restrict__ colv) {
    int i = blockIdx.x * blockDim.x + threadIdx.x;
    if (i >= total) return;
    colv[i] = inv[(i >= split ? N_ : 0) + col[i]];
}

// csum[n][j2] = inv[n]*cfg[n][j2] + sum_s colv*cfg[s][j2]   (unroll-2)
__global__ void k_csum_gather(const float2* __restrict__ cfg2, const float* __restrict__ inv,
                              const int* __restrict__ roff, const int* __restrict__ col,
                              const float* __restrict__ colv, float2* __restrict__ csum2) {
    int t = blockIdx.x * blockDim.x + threadIdx.x;
    if (t >= N_ * 45) return;
    int n = t / 45, j2 = t - n * 45;
    float iv = inv[n];
    float2 a = cfg2[t];
    a.x *= iv; a.y *= iv;
    int e = roff[n], p1 = roff[n + 1];
    for (; e + 1 < p1; e += 2) {
        int s0 = col[e], s1 = col[e + 1];
        float i0 = colv[e], i1 = colv[e + 1];
        float2 v0 = cfg2[(size_t)s0 * 45 + j2];
        float2 v1 = cfg2[(size_t)s1 * 45 + j2];
        a.x = fmaf(v0.x, i0, a.x); a.y = fmaf(v0.y, i0, a.y);
        a.x = fmaf(v1.x, i1, a.x); a.y = fmaf(v1.y, i1, a.y);
    }
    if (e < p1) {
        int s0 = col[e];
        float i0 = colv[e];
        float2 v0 = cfg2[(size_t)s0 * 45 + j2];
        a.x = fmaf(v0.x, i0, a.x); a.y = fmaf(v0.y, i0, a.y);
    }
    csum2[t] = a;
}

// pre-MLP, one thread per row
__global__ void k_pre(const float* __restrict__ cfg, const float* __restrict__ nfw,
                      const float* __restrict__ w1, const float* __restrict__ w2,
                      const float* __restrict__ b2, float* __restrict__ x) {
    int r = blockIdx.x * blockDim.x + threadIdx.x;
    if (r >= N_ * C_) return;
    int n = r / C_;
    float h1[H_];
    const float4* nf4 = (const float4*)(nfw + (size_t)n * H_);
    #pragma unroll
    for (int q = 0; q < 8; ++q) {
        float4 v = nf4[q];
        h1[4 * q + 0] = v.x; h1[4 * q + 1] = v.y; h1[4 * q + 2] = v.z; h1[4 * q + 3] = v.w;
    }
    const float2* c2 = (const float2*)(cfg + (size_t)r * CFGF);
    for (int kc = 0; kc < CFGF / 2; ++kc) {
        float2 cv = c2[kc];
        float cs[2] = {cv.x, cv.y};
        #pragma unroll
        for (int j = 0; j < 2; ++j) {
            int k = kc * 2 + j;
            #pragma unroll
            for (int h = 0; h < H_; ++h) h1[h] = fmaf(cs[j], w1[k * H_ + h], h1[h]);
        }
    }
    #pragma unroll
    for (int h = 0; h < H_; ++h) h1[h] = lrelu(h1[h]);
    float acc[H_];
    #pragma unroll
    for (int h = 0; h < H_; ++h) acc[h] = b2[h];
    #pragma unroll
    for (int k = 0; k < H_; ++k) {
        float v = h1[k];
        #pragma unroll
        for (int h = 0; h < H_; ++h) acc[h] = fmaf(v, w2[k * H_ + h], acc[h]);
    }
    float4* o = (float4*)(x + (size_t)r * H_);
    #pragma unroll
    for (int q = 0; q < 8; ++q)
        o[q] = make_float4(lrelu(acc[4 * q]), lrelu(acc[4 * q + 1]),
                           lrelu(acc[4 * q + 2]), lrelu(acc[4 * q + 3]));
}

// FUSED gather + GC-MLP, thread-per-row. csum@w1c hoisted BEFORE gather
// (independent VALU work overlaps gather latency); colv kills the inv chain.
__global__ void k_gcfused(const float4* __restrict__ xin4, const float* __restrict__ csum,
                          const float* __restrict__ inv, const int* __restrict__ roff,
                          const int* __restrict__ col, const float* __restrict__ colv,
                          const float* __restrict__ w1, const float* __restrict__ b1,
                          const float* __restrict__ w2, const float* __restrict__ b2,
                          float4* __restrict__ xout4) {
    int r = blockIdx.x * blockDim.x + threadIdx.x;
    if (r >= N_ * C_) return;
    int n = r / C_, c = r - n * C_;
    float iv = inv[n];

    // --- csum @ w1c first: ~600 independent FMAs to overlap with gather ---
    float t1[H_];
    #pragma unroll
    for (int h = 0; h < H_; ++h) t1[h] = 0.0f;
    const float2* c2 = (const float2*)(csum + (size_t)r * CFGF);
    for (int kc = 0; kc < CFGF / 2; ++kc) {
        float2 cv = c2[kc];
        float cs[2] = {cv.x, cv.y};
        #pragma unroll
        for (int j = 0; j < 2; ++j) {
            int k = kc * 2 + j;
            #pragma unroll
            for (int h = 0; h < H_; ++h) t1[h] = fmaf(cs[j], w1[k * H_ + h], t1[h]);
        }
    }

    // --- gather ---
    float xs[H_];
    const float4* sp = xin4 + (size_t)r * 8;
    #pragma unroll
    for (int q = 0; q < 8; ++q) {
        float4 v = sp[q];
        xs[4 * q + 0] = v.x * iv; xs[4 * q + 1] = v.y * iv;
        xs[4 * q + 2] = v.z * iv; xs[4 * q + 3] = v.w * iv;
    }
    int e = roff[n], p1 = roff[n + 1];
    for (; e + 1 < p1; e += 2) {
        int s0 = col[e], s1 = col[e + 1];
        float i0 = colv[e], i1 = colv[e + 1];
        const float4* np0 = xin4 + ((size_t)s0 * C_ + c) * 8;
        const float4* np1 = xin4 + ((size_t)s1 * C_ + c) * 8;
        #pragma unroll
        for (int q = 0; q < 8; ++q) {
            float4 v0 = np0[q];
            float4 v1 = np1[q];
            xs[4 * q + 0] = fmaf(v0.x, i0, xs[4 * q + 0]);
            xs[4 * q + 1] = fmaf(v0.y, i0, xs[4 * q + 1]);
            xs[4 * q + 2] = fmaf(v0.z, i0, xs[4 * q + 2]);
            xs[4 * q + 3] = fmaf(v0.w, i0, xs[4 * q + 3]);
            xs[4 * q + 0] = fmaf(v1.x, i1, xs[4 * q + 0]);
            xs[4 * q + 1] = fmaf(v1.y, i1, xs[4 * q + 1]);
            xs[4 * q + 2] = fmaf(v1.z, i1, xs[4 * q + 2]);
            xs[4 * q + 3] = fmaf(v1.w, i1, xs[4 * q + 3]);
        }
    }
    if (e < p1) {
        int s0 = col[e];
        float i0 = colv[e];
        const float4* np = xin4 + ((size_t)s0 * C_ + c) * 8;
        #pragma unroll
        for (int q = 0; q < 8; ++q) {
            float4 v = np[q];
            xs[4 * q + 0] = fmaf(v.x, i0, xs[4 * q + 0]);
            xs[4 * q + 1] = fmaf(v.y, i0, xs[4 * q + 1]);
            xs[4 * q + 2] = fmaf(v.z, i0, xs[4 * q + 2]);
            xs[4 * q + 3] = fmaf(v.w, i0, xs[4 * q + 3]);
        }
    }

    // --- rest of MLP ---
    #pragma unroll
    for (int k = 0; k < H_; ++k) {
        float v = xs[k];
        #pragma unroll
        for (int h = 0; h < H_; ++h) t1[h] = fmaf(v, w1[(CFGF + k) * H_ + h], t1[h]);
    }
    float h1[H_];
    #pragma unroll
    for (int h = 0; h < H_; ++h) h1[h] = lrelu(fmaf(iv, t1[h], b1[h]));
    float acc[H_];
    #pragma unroll
    for (int h = 0; h < H_; ++h) acc[h] = b2[h];
    #pragma unroll
    for (int k = 0; k < H_; ++k) {
        float v = h1[k];
        #pragma unroll
        for (int h = 0; h < H_; ++h) acc[h] = fmaf(v, w2[k * H_ + h], acc[h]);
    }
    float4* o = xout4 + (size_t)r * 8;
    #pragma unroll
    for (int q = 0; q < 8; ++q) {
        float4 v = sp[q];   // L1/L2-hot reload for residual
        v.x += lrelu(acc[4 * q + 0]); v.y += lrelu(acc[4 * q + 1]);
        v.z += lrelu(acc[4 * q + 2]); v.w += lrelu(acc[4 * q + 3]);
        o[q] = v;
    }
}

// op_sum: group via closed form n/NPG
__global__ void k_opsum(const float4* __restrict__ xf4, const float4* __restrict__ xb4,
                        const int* __restrict__ sel,
                        float* __restrict__ osum, float* __restrict__ cnt) {
    __shared__ float4 ls[6 * G_ * 40];
    __shared__ float lc[6 * G_];
    for (int i = threadIdx.x; i < 6 * G_ * 40; i += blockDim.x) ls[i] = make_float4(0.f, 0.f, 0.f, 0.f);
    if (threadIdx.x < 6 * G_) lc[threadIdx.x] = 0.0f;
    __syncthreads();
    int j4 = threadIdx.x % 40, i = threadIdx.x / 40;
    const int NPB = CDIV(N_, 512);
    int start = blockIdx.x * NPB;
    int end = min(start + NPB, N_);
    if (i < 6) {
        for (int n = start + i; n < end; n += 6) {
            int g = n / NPG;
            const float4* xr = sel[n] ? xb4 : xf4;
            float4 v = xr[(size_t)n * 40 + j4];
            int o = (i * G_ + g) * 40 + j4;
            float4 cacc = ls[o];
            cacc.x += v.x; cacc.y += v.y; cacc.z += v.z; cacc.w += v.w;
            ls[o] = cacc;
            if (j4 == 0) lc[i * G_ + g] += 1.0f;
        }
    }
    __syncthreads();
    for (int idx = threadIdx.x; idx < G_ * 40; idx += blockDim.x) {
        float4 s = ls[idx];
        #pragma unroll
        for (int q = 1; q < 6; ++q) {
            float4 v = ls[q * G_ * 40 + idx];
            s.x += v.x; s.y += v.y; s.z += v.z; s.w += v.w;
        }
        int g = idx / 40, j = idx - g * 40;
        float* o = osum + (size_t)g * XROW + j * 4;
        atomicAdd(o + 0, s.x); atomicAdd(o + 1, s.y);
        atomicAdd(o + 2, s.z); atomicAdd(o + 3, s.w);
    }
    if (threadIdx.x < G_) {
        float c = 0.0f;
        #pragma unroll
        for (int q = 0; q < 6; ++q) c += lc[q * G_ + threadIdx.x];
        atomicAdd(&cnt[threadIdx.x], c);
    }
}

// cfg_sum: group via closed form e/EPG
__global__ void k_cfgsum(const float4* __restrict__ xf4, const float4* __restrict__ xb4,
                         const int* __restrict__ sel, const int* __restrict__ cdst,
                         float* __restrict__ gsum) {
    __shared__ float4 ls[6 * G_ * 40];
    for (int i = threadIdx.x; i < 6 * G_ * 40; i += blockDim.x) ls[i] = make_float4(0.f, 0.f, 0.f, 0.f);
    __syncthreads();
    int j4 = threadIdx.x % 40, i = threadIdx.x / 40;
    const int EPB = CDIV(NC_, 64);
    int start = blockIdx.x * EPB;
    int end = min(start + EPB, NC_);
    if (i < 6) {
        for (int e = start + i; e < end; e += 6) {
            int g = e / EPG;
            int n = cdst[e];
            const float4* xr = sel[n] ? xb4 : xf4;
            float4 v = xr[(size_t)n * 40 + j4];
            int o = (i * G_ + g) * 40 + j4;
            float4 cacc = ls[o];
            cacc.x += v.x; cacc.y += v.y; cacc.z += v.z; cacc.w += v.w;
            ls[o] = cacc;
        }
    }
    __syncthreads();
    for (int idx = threadIdx.x; idx < G_ * 40; idx += blockDim.x) {
        float4 s = ls[idx];
        #pragma unroll
        for (int q = 1; q < 6; ++q) {
            float4 v = ls[q * G_ * 40 + idx];
            s.x += v.x; s.y += v.y; s.z += v.z; s.w += v.w;
        }
        int g = idx / 40, j = idx - g * 40;
        float* o = gsum + (size_t)g * XROW + j * 4;
        atomicAdd(o + 0, s.x); atomicAdd(o + 1, s.y);
        atomicAdd(o + 2, s.z); atomicAdd(o + 3, s.w);
    }
}

__global__ void k_final(const float* __restrict__ osum, const float* __restrict__ gsum,
                        const float* __restrict__ cnt, const float* __restrict__ pw1,
                        const float* __restrict__ pw2, float* __restrict__ out) {
    __shared__ float sw1[3 * H_ * H_];
    __shared__ float sw2[H_];
    for (int i = threadIdx.x; i < 3 * H_ * H_; i += blockDim.x) sw1[i] = pw1[i];
    if (threadIdx.x < H_) sw2[threadIdx.x] = pw2[threadIdx.x];
    __syncthreads();
    int t = threadIdx.x;
    if (t >= G_ * C_) return;
    int g = t / C_;
    const float* os = osum + (size_t)t * H_;
    const float* cs = gsum + (size_t)t * H_;
    float icnt = 1.0f / cnt[g];
    float a0[H_], a1[H_], a2[H_];
    float s1 = 0.0f, s2 = 0.0f;
    #pragma unroll
    for (int h = 0; h < H_; ++h) {
        float v1 = os[h], v2 = cs[h];
        a0[h] = v1 * icnt;
        a1[h] = v1; s1 = fmaf(v1, v1, s1);
        a2[h] = v2; s2 = fmaf(v2, v2, s2);
    }
    float r1 = 1.0f / sqrtf(fmaxf(s1, 1e-12f));
    float r2 = 1.0f / sqrtf(fmaxf(s2, 1e-12f));
    #pragma unroll
    for (int h = 0; h < H_; ++h) { a1[h] *= r1; a2[h] *= r2; }
    float o = 0.0f;
    #pragma unroll
    for (int h = 0; h < H_; ++h) {
        float a = 0.0f;
        #pragma unroll
        for (int k = 0; k < H_; ++k) a = fmaf(a0[k], sw1[k * H_ + h], a);
        #pragma unroll
        for (int k = 0; k < H_; ++k) a = fmaf(a1[k], sw1[(H_ + k) * H_ + h], a);
        #pragma unroll
        for (int k = 0; k < H_; ++k) a = fmaf(a2[k], sw1[(2 * H_ + k) * H_ + h], a);
        o = fmaf(lrelu(a), sw2[h], o);
    }
    out[t] = o;
}

extern "C" void kernel_launch(void* const* d_in, const int* in_sizes, int n_in,
                              void* d_out, int out_size, void* d_ws, size_t ws_size,
                              hipStream_t stream) {
    const float* op_feats     = (const float*)d_in[0];
    const float* config_feats = (const float*)d_in[1];
    const int*   op_ids       = (const int*)d_in[2];
    const int*   selected     = (const int*)d_in[3];
    const int*   feed_src     = (const int*)d_in[4];
    const int*   feed_dst     = (const int*)d_in[5];
    const int*   sfeed_src    = (const int*)d_in[6];
    const int*   sfeed_dst    = (const int*)d_in[7];
    const int*   config_dst   = (const int*)d_in[9];
    const int*   sconfig_dst  = (const int*)d_in[11];
    const float* emb          = (const float*)d_in[14];
    const float* pre_w1       = (const float*)d_in[15];
    const float* pre_b1       = (const float*)d_in[16];
    const float* pre_w2       = (const float*)d_in[17];
    const float* pre_b2       = (const float*)d_in[18];
    const float* gc_w1[2]     = {(const float*)d_in[19], (const float*)d_in[23]};
    const float* gc_b1[2]     = {(const float*)d_in[20], (const float*)d_in[24]};
    const float* gc_w2[2]     = {(const float*)d_in[21], (const float*)d_in[25]};
    const float* gc_b2[2]     = {(const float*)d_in[22], (const float*)d_in[26]};
    const float* post_w1      = (const float*)d_in[27];
    const float* post_w2      = (const float*)d_in[28];

    int E0 = in_sizes[4], E1 = in_sizes[6];
    int ecnt = 2 * (E0 + E1);

    char* ws = (char*)d_ws;
    size_t off = 0;
    auto alloc = [&](size_t bytes) { void* p = ws + off; off += (bytes + 255) & ~(size_t)255; return p; };
    float* nfw   = (float*)alloc((size_t)N_ * H_ * 4);
    float* nfwop = (float*)alloc((size_t)NUMOPS * H_ * 4);
    float* cfg   = (float*)alloc((size_t)N_ * CROW * 4);
    float* csum  = (float*)alloc((size_t)N_ * CROW * 4);
    float* xf    = (float*)alloc((size_t)N_ * XROW * 4);
    float* xb    = (float*)alloc((size_t)N_ * XROW * 4);
    float* xscr  = (float*)alloc((size_t)N_ * XROW * 4);
    float* invA  = (float*)alloc((size_t)2 * N_ * 4);
    int*   degA  = (int*)alloc((size_t)2 * N_ * 4);
    int*   roffA = (int*)alloc((size_t)(2 * N_ + 1) * 4);
    int*   curA  = (int*)alloc((size_t)2 * N_ * 4);
    int*   aux   = (int*)alloc((size_t)1024 * 4);
    int*   colA  = (int*)alloc((size_t)ecnt * 4);
    float* colvA = (float*)alloc((size_t)ecnt * 4);
    float* osum  = (float*)alloc((size_t)G_ * XROW * 4);
    float* gsum  = (float*)alloc((size_t)G_ * XROW * 4);
    float* cntb  = (float*)alloc((size_t)G_ * 4);

    const int NB1 = CDIV(2 * N_, 256);

    k_nfwop<<<CDIV(NUMOPS * H_, 256), 256, 0, stream>>>(emb, pre_w1, pre_b1, nfwop);
    k_nfw<<<CDIV(N_, 256), 256, 0, stream>>>(op_feats, op_ids, nfwop, pre_w1, nfw);

    // ---- shared CSR build for both passes ----
    hipMemsetAsync(degA, 0, (size_t)2 * N_ * 4, stream);
    k_deg2<<<CDIV(E0 + E1, 256), 256, 0, stream>>>(feed_src, feed_dst, E0,
                                                   sfeed_src, sfeed_dst, E1, degA);
    k_inv2<<<CDIV(2 * N_, 256), 256, 0, stream>>>(degA, invA);
    k_scan1<<<NB1, 256, 0, stream>>>(degA, roffA, aux);
    k_scan2<<<1, 1024, 0, stream>>>(aux, NB1);
    k_scan3<<<CDIV(2 * N_, 256), 256, 0, stream>>>(roffA, aux, curA, ecnt);
    k_fill2<<<CDIV(E0 + E1, 256), 256, 0, stream>>>(feed_src, feed_dst, E0,
                                                    sfeed_src, sfeed_dst, E1, curA, colA);
    k_colinv<<<CDIV(ecnt, 256), 256, 0, stream>>>(colA, invA, 2 * E0, ecnt, colvA);

    for (int p = 0; p < 2; ++p) {
        const int* cdst = p ? sconfig_dst : config_dst;
        float* x0 = p ? xb : xf;
        const float* ivp = invA + (size_t)p * N_;
        const int* roffp = roffA + (size_t)p * N_;

        hipMemsetAsync(cfg, 0, (size_t)N_ * CROW * 4, stream);
        k_cfg_scatter<<<CDIV(NC_ * CROW, 256), 256, 0, stream>>>(config_feats, cdst, cfg);
        k_csum_gather<<<CDIV(N_ * 45, 256), 256, 0, stream>>>((const float2*)cfg, ivp, roffp,
                                                              colA, colvA, (float2*)csum);
        k_pre<<<CDIV(N_ * C_, 256), 256, 0, stream>>>(cfg, nfw, pre_w1, pre_w2, pre_b2, x0);

        k_gcfused<<<CDIV(N_ * C_, 256), 256, 0, stream>>>((const float4*)x0, csum, ivp, roffp,
                                                          colA, colvA, gc_w1[0], gc_b1[0],
                                                          gc_w2[0], gc_b2[0], (float4*)xscr);
        k_gcfused<<<CDIV(N_ * C_, 256), 256, 0, stream>>>((const float4*)xscr, csum, ivp, roffp,
                                                          colA, colvA, gc_w1[1], gc_b1[1],
                                                          gc_w2[1], gc_b2[1], (float4*)x0);
    }

    hipMemsetAsync(osum, 0, (size_t)(2 * G_ * XROW + G_) * 4, stream);
    k_opsum<<<512, 256, 0, stream>>>((const float4*)xf, (const float4*)xb, selected, osum, cntb);
    k_cfgsum<<<64, 256, 0, stream>>>((const float4*)xf, (const float4*)xb, selected,
                                     config_dst, gsum);
    k_final<<<1, 128, 0, stream>>>(osum, gsum, cntb, post_w1, post_w2, (float*)d_out);
}